// Round 2
// baseline (337.263 us; speedup 1.0000x reference)
//
#include <hip/hip_runtime.h>
#include <hip/hip_bf16.h>

#define B_   4
#define N_   2048
#define IN_  256
#define OUT_ 256
#define H_   4
#define HD_  64
#define LN_EPS 1e-5f
#define YCD_ 4            // y-chunks for deg pass
#define YCO_ 2            // y-chunks for out1 pass

typedef __bf16 bf16x8 __attribute__((ext_vector_type(8)));
typedef float  f32x4  __attribute__((ext_vector_type(4)));
typedef unsigned short u16x8 __attribute__((ext_vector_type(8)));
typedef unsigned int   u32x4 __attribute__((ext_vector_type(4)));

__device__ __forceinline__ unsigned short f2bf(float x) {
    unsigned int u = __float_as_uint(x);
    return (unsigned short)((u + 0x7FFFu + ((u >> 16) & 1u)) >> 16);
}
__device__ __forceinline__ float bf2f(unsigned short u) {
    return __uint_as_float((unsigned int)u << 16);
}
__device__ __forceinline__ unsigned int cvtpk(float lo, float hi) {
    unsigned int r;
    asm("v_cvt_pk_bf16_f32 %0, %1, %2" : "=v"(r) : "v"(lo), "v"(hi));
    return r;
}

// ---------------------------------------------------------------------------
// conv: nf -> bf16 (nfb), W_{lin,q,k} -> bf16 transposed (Wt[z][n][k])
// ---------------------------------------------------------------------------
__global__ __launch_bounds__(256) void conv_kernel(
    const float* __restrict__ nf, const float* __restrict__ Wl,
    const float* __restrict__ Wq, const float* __restrict__ Wk,
    unsigned short* __restrict__ nfb, unsigned short* __restrict__ Wt)
{
    const int bid = blockIdx.x, tid = threadIdx.x;
    if (bid < 1024) {
        size_t i = ((size_t)bid * 256 + tid) * 8;
        u16x8 o;
        #pragma unroll
        for (int j = 0; j < 8; j++) o[j] = f2bf(nf[i + j]);
        *(u16x8*)&nfb[i] = o;
    } else {
        int t = (bid - 1024) * 256 + tid;   // 0..196607
        int z = t >> 16;
        int l = t & 65535;
        int k = l & 255, n = l >> 8;
        const float* W = (z == 0) ? Wl : (z == 1 ? Wq : Wk);
        Wt[(size_t)z * 65536 + n * 256 + k] = f2bf(W[k * 256 + n]);
    }
}

// ---------------------------------------------------------------------------
// gemm3: X/q/k = lrelu(nfb @ W + bias), barrier-free fragment GEMM
// ---------------------------------------------------------------------------
__global__ __launch_bounds__(256) void gemm3_kernel(
    const unsigned short* __restrict__ nfb, const unsigned short* __restrict__ Wt3,
    const float* __restrict__ bl,
    unsigned short* __restrict__ qb, unsigned short* __restrict__ kb,
    unsigned short* __restrict__ Xt)
{
    const int z  = blockIdx.z;
    const int m0 = blockIdx.x * 64, n0 = blockIdx.y * 64;
    const int tid = threadIdx.x, wave = tid >> 6, lane = tid & 63;
    const int lq = lane >> 4, lr = lane & 15;
    const unsigned short* Wt = Wt3 + (size_t)z * 65536;

    f32x4 acc[4] = {};
    #pragma unroll 4
    for (int k0 = 0; k0 < IN_; k0 += 32) {
        bf16x8 af = *(const bf16x8*)&nfb[(size_t)(m0 + wave * 16 + lr) * IN_ + k0 + lq * 8];
        #pragma unroll
        for (int f = 0; f < 4; f++) {
            bf16x8 bfr = *(const bf16x8*)&Wt[(size_t)(n0 + f * 16 + lr) * IN_ + k0 + lq * 8];
            acc[f] = __builtin_amdgcn_mfma_f32_16x16x32_bf16(af, bfr, acc[f], 0, 0, 0);
        }
    }

    #pragma unroll
    for (int f = 0; f < 4; f++) {
        int c = n0 + f * 16 + lr;
        float bias = (z == 0) ? bl[c] : 0.0f;
        #pragma unroll
        for (int r = 0; r < 4; r++) {
            int m = m0 + wave * 16 + lq * 4 + r;
            float v = acc[f][r] + bias;
            v = (v >= 0.f) ? v : 0.01f * v;
            unsigned short bv = f2bf(v);
            if (z == 0) {
                int n = m & (N_ - 1);
                int h = c >> 6, d = c & 63;
                Xt[(((size_t)(m >> 11) * H_ + h) * HD_ + d) * N_ + n] = bv;
            } else {
                unsigned short* dst = (z == 1) ? qb : kb;
                dst[(size_t)m * OUT_ + c] = bv;
            }
        }
    }
}

// ---------------------------------------------------------------------------
// deg: deg[b,h,x] += sum_{y in chunk} adj*sigmoid(qk/8)  (atomic partials)
// ---------------------------------------------------------------------------
__global__ __launch_bounds__(256) void deg_kernel(
    const float* __restrict__ adj,
    const unsigned short* __restrict__ qb,
    const unsigned short* __restrict__ kb,
    float* __restrict__ deg)
{
    const int b = blockIdx.y, x0 = blockIdx.x * 16, yc = blockIdx.z;
    const int tid = threadIdx.x, h = tid >> 6, lane = tid & 63;
    const int lq = lane >> 4, lr = lane & 15;
    const float sc = -0.125f * 1.44269504088896f;
    __shared__ __align__(16) float ads[16][68];

    bf16x8 qf[2];
    #pragma unroll
    for (int ks = 0; ks < 2; ks++)
        qf[ks] = *(const bf16x8*)&qb[(size_t)(b * N_ + x0 + lr) * OUT_ + h * HD_ + ks * 32 + lq * 8];

    float degp[4] = {};

    for (int yt = 0; yt < N_ / YCD_ / 64; yt++) {
        const int y0 = yc * (N_ / YCD_) + yt * 64;
        {   // stage adj tile [16x][64y] coalesced
            int r = tid >> 4, c = (tid & 15) * 4;
            *(f32x4*)&ads[r][c] = *(const f32x4*)&adj[((size_t)b * N_ + x0 + r) * N_ + y0 + c];
        }
        f32x4 S[4] = {};
        #pragma unroll
        for (int yb = 0; yb < 4; yb++) {
            #pragma unroll
            for (int ks = 0; ks < 2; ks++) {
                bf16x8 kf = *(const bf16x8*)&kb[(size_t)(b * N_ + y0 + yb * 16 + lr) * OUT_ + h * HD_ + ks * 32 + lq * 8];
                S[yb] = __builtin_amdgcn_mfma_f32_16x16x32_bf16(qf[ks], kf, S[yb], 0, 0, 0);
            }
        }
        __syncthreads();
        #pragma unroll
        for (int yb = 0; yb < 4; yb++) {
            #pragma unroll
            for (int r = 0; r < 4; r++) {
                float a = ads[lq * 4 + r][yb * 16 + lr];
                float att = __builtin_amdgcn_rcpf(1.f + exp2f(S[yb][r] * sc));
                degp[r] += a * att;
            }
        }
        __syncthreads();
    }
    #pragma unroll
    for (int r = 0; r < 4; r++) {
        float v = degp[r];
        v += __shfl_xor(v, 1); v += __shfl_xor(v, 2);
        v += __shfl_xor(v, 4); v += __shfl_xor(v, 8);
        degp[r] = v;
    }
    if (lr == 0) {
        #pragma unroll
        for (int r = 0; r < 4; r++)
            atomicAdd(&deg[((size_t)b * H_ + h) * N_ + x0 + lq * 4 + r], degp[r]);
    }
}

// ---------------------------------------------------------------------------
// scale: Xs = Xt * dis_y (bf16); also writes dis[] (rows d==0)
// ---------------------------------------------------------------------------
__global__ __launch_bounds__(256) void scale_kernel(
    const unsigned short* __restrict__ Xt, const float* __restrict__ deg,
    unsigned short* __restrict__ Xs, float* __restrict__ dis)
{
    const int t = blockIdx.x * 256 + threadIdx.x;   // 262144 threads
    const size_t idx = (size_t)t * 8;
    const int bh = t >> 14;
    const int y  = (int)(idx & (N_ - 1));
    f32x4 g0 = *(const f32x4*)&deg[bh * N_ + y];
    f32x4 g1 = *(const f32x4*)&deg[bh * N_ + y + 4];
    float dv[8];
    #pragma unroll
    for (int j = 0; j < 4; j++) {
        dv[j]     = (g0[j] > 0.f) ? rsqrtf(g0[j]) : 0.f;
        dv[4 + j] = (g1[j] > 0.f) ? rsqrtf(g1[j]) : 0.f;
    }
    if ((t & 16383) < 256) {   // d==0 row: persist dis for out2
        f32x4 o0 = {dv[0], dv[1], dv[2], dv[3]};
        f32x4 o1 = {dv[4], dv[5], dv[6], dv[7]};
        *(f32x4*)&dis[bh * N_ + y]     = o0;
        *(f32x4*)&dis[bh * N_ + y + 4] = o1;
    }
    u16x8 x = *(const u16x8*)&Xt[idx];
    u32x4 o;
    o[0] = cvtpk(bf2f(x[0]) * dv[0], bf2f(x[1]) * dv[1]);
    o[1] = cvtpk(bf2f(x[2]) * dv[2], bf2f(x[3]) * dv[3]);
    o[2] = cvtpk(bf2f(x[4]) * dv[4], bf2f(x[5]) * dv[5]);
    o[3] = cvtpk(bf2f(x[6]) * dv[6], bf2f(x[7]) * dv[7]);
    *(u32x4*)&Xs[idx] = o;
}

// ---------------------------------------------------------------------------
// out1: partial Y over a y-chunk: Y += (adj*att) @ Xs   (dis_y folded in Xs)
// ---------------------------------------------------------------------------
__global__ __launch_bounds__(256) void out1_kernel(
    const float* __restrict__ adj,
    const unsigned short* __restrict__ qb,
    const unsigned short* __restrict__ kb,
    const unsigned short* __restrict__ Xs,
    float* __restrict__ Ypart)
{
    const int b = blockIdx.y, x0 = blockIdx.x * 16, yc = blockIdx.z;
    const int tid = threadIdx.x, h = tid >> 6, lane = tid & 63;
    const int lq = lane >> 4, lr = lane & 15;
    const float sc = -0.125f * 1.44269504088896f;
    __shared__ __align__(16) float ads[16][68];
    __shared__ __align__(16) float wt[4][16][68];

    bf16x8 qf[2];
    #pragma unroll
    for (int ks = 0; ks < 2; ks++)
        qf[ks] = *(const bf16x8*)&qb[(size_t)(b * N_ + x0 + lr) * OUT_ + h * HD_ + ks * 32 + lq * 8];

    f32x4 Y[4] = {};

    for (int yt = 0; yt < N_ / YCO_ / 64; yt++) {
        const int y0 = yc * (N_ / YCO_) + yt * 64;
        {
            int r = tid >> 4, c = (tid & 15) * 4;
            *(f32x4*)&ads[r][c] = *(const f32x4*)&adj[((size_t)b * N_ + x0 + r) * N_ + y0 + c];
        }
        f32x4 S[4] = {};
        #pragma unroll
        for (int yb = 0; yb < 4; yb++) {
            #pragma unroll
            for (int ks = 0; ks < 2; ks++) {
                bf16x8 kf = *(const bf16x8*)&kb[(size_t)(b * N_ + y0 + yb * 16 + lr) * OUT_ + h * HD_ + ks * 32 + lq * 8];
                S[yb] = __builtin_amdgcn_mfma_f32_16x16x32_bf16(qf[ks], kf, S[yb], 0, 0, 0);
            }
        }
        __syncthreads();
        // w = adj * att (fp32) into wave-private LDS tile
        #pragma unroll
        for (int yb = 0; yb < 4; yb++) {
            #pragma unroll
            for (int r = 0; r < 4; r++) {
                float a = ads[lq * 4 + r][yb * 16 + lr];
                float att = __builtin_amdgcn_rcpf(1.f + exp2f(S[yb][r] * sc));
                wt[h][lq * 4 + r][yb * 16 + lr] = a * att;
            }
        }
        // PV: frag-read w (fp32 -> cvt_pk bf16), MFMA vs pre-scaled Xs
        #pragma unroll
        for (int ks = 0; ks < 2; ks++) {
            f32x4 w0 = *(const f32x4*)&wt[h][lr][ks * 32 + lq * 8];
            f32x4 w1 = *(const f32x4*)&wt[h][lr][ks * 32 + lq * 8 + 4];
            union { u32x4 u; bf16x8 v; } wu;
            wu.u[0] = cvtpk(w0[0], w0[1]);
            wu.u[1] = cvtpk(w0[2], w0[3]);
            wu.u[2] = cvtpk(w1[0], w1[1]);
            wu.u[3] = cvtpk(w1[2], w1[3]);
            #pragma unroll
            for (int db = 0; db < 4; db++) {
                bf16x8 xf = *(const bf16x8*)&Xs[(((size_t)b * H_ + h) * HD_ + db * 16 + lr) * N_ + y0 + ks * 32 + lq * 8];
                Y[db] = __builtin_amdgcn_mfma_f32_16x16x32_bf16(wu.v, xf, Y[db], 0, 0, 0);
            }
        }
        __syncthreads();
    }

    #pragma unroll
    for (int db = 0; db < 4; db++)
        #pragma unroll
        for (int r = 0; r < 4; r++)
            Ypart[((size_t)(yc * B_ + b) * N_ + x0 + lq * 4 + r) * OUT_ + h * HD_ + db * 16 + lr] = Y[db][r];
}

// ---------------------------------------------------------------------------
// out2: sum partials, * dis_x, LayerNorm, write
// ---------------------------------------------------------------------------
__global__ __launch_bounds__(256) void out2_kernel(
    const float* __restrict__ Yp, const float* __restrict__ dis,
    const float* __restrict__ lng, const float* __restrict__ lnb,
    float* __restrict__ out)
{
    const int row = blockIdx.x;           // b*N + x
    const int c = threadIdx.x;
    const size_t PS = (size_t)B_ * N_ * OUT_;
    const size_t base = (size_t)row * OUT_ + c;
    float v = Yp[base];
    #pragma unroll
    for (int p = 1; p < YCO_; p++) v += Yp[base + (size_t)p * PS];
    const int b = row >> 11, x = row & (N_ - 1);
    v *= dis[((size_t)b * H_ + (c >> 6)) * N_ + x];

    float s1 = v, s2 = v * v;
    #pragma unroll
    for (int d = 1; d < 64; d <<= 1) { s1 += __shfl_xor(s1, d); s2 += __shfl_xor(s2, d); }
    __shared__ float red[2][4];
    if ((c & 63) == 0) { red[0][c >> 6] = s1; red[1][c >> 6] = s2; }
    __syncthreads();
    float t1 = red[0][0] + red[0][1] + red[0][2] + red[0][3];
    float t2 = red[1][0] + red[1][1] + red[1][2] + red[1][3];
    float mu  = t1 * (1.f / 256.f);
    float var = t2 * (1.f / 256.f) - mu * mu;
    float rs  = rsqrtf(var + LN_EPS);
    out[base] = (v - mu) * rs * lng[c] + lnb[c];
}

extern "C" void kernel_launch(void* const* d_in, const int* in_sizes, int n_in,
                              void* d_out, int out_size, void* d_ws, size_t ws_size,
                              hipStream_t stream) {
    const float* nf  = (const float*)d_in[0];
    const float* adj = (const float*)d_in[1];
    const float* Wl  = (const float*)d_in[2];
    const float* bl  = (const float*)d_in[3];
    const float* Wq  = (const float*)d_in[4];
    const float* Wk  = (const float*)d_in[5];
    const float* lng = (const float*)d_in[6];
    const float* lnb = (const float*)d_in[7];
    float* out = (float*)d_out;

    char* w = (char*)d_ws;
    unsigned short* nfb = (unsigned short*)w;  w += (size_t)B_ * N_ * IN_ * 2;       // 4 MB
    unsigned short* Wt  = (unsigned short*)w;  w += (size_t)3 * IN_ * OUT_ * 2;      // 384 KB
    unsigned short* qb  = (unsigned short*)w;  w += (size_t)B_ * N_ * OUT_ * 2;      // 4 MB
    unsigned short* kb  = (unsigned short*)w;  w += (size_t)B_ * N_ * OUT_ * 2;      // 4 MB
    unsigned short* Xt  = (unsigned short*)w;  w += (size_t)B_ * N_ * OUT_ * 2;      // 4 MB
    unsigned short* Xs  = (unsigned short*)w;  w += (size_t)B_ * N_ * OUT_ * 2;      // 4 MB
    float* deg = (float*)w;                    w += (size_t)B_ * H_ * N_ * 4;        // 128 KB
    float* dis = (float*)w;                    w += (size_t)B_ * H_ * N_ * 4;        // 128 KB
    float* Yp  = (float*)w;                    w += (size_t)YCO_ * B_ * N_ * OUT_ * 4; // 16.8 MB

    hipMemsetAsync(deg, 0, (size_t)B_ * H_ * N_ * 4, stream);
    conv_kernel <<<1792, 256, 0, stream>>>(nf, Wl, Wq, Wk, nfb, Wt);
    gemm3_kernel<<<dim3(128, 4, 3), 256, 0, stream>>>(nfb, Wt, bl, qb, kb, Xt);
    deg_kernel  <<<dim3(N_ / 16, B_, YCD_), 256, 0, stream>>>(adj, qb, kb, deg);
    scale_kernel<<<1024, 256, 0, stream>>>(Xt, deg, Xs, dis);
    out1_kernel <<<dim3(N_ / 16, B_, YCO_), 256, 0, stream>>>(adj, qb, kb, Xs, Yp);
    out2_kernel <<<B_ * N_, 256, 0, stream>>>(Yp, dis, lng, lnb, out);
}

// Round 3
// 315.263 us; speedup vs baseline: 1.0698x; 1.0698x over previous
//
#include <hip/hip_runtime.h>
#include <hip/hip_bf16.h>

#define B_   4
#define N_   2048
#define IN_  256
#define OUT_ 256
#define H_   4
#define HD_  64
#define LN_EPS 1e-5f

typedef __bf16 bf16x8 __attribute__((ext_vector_type(8)));
typedef float  f32x4  __attribute__((ext_vector_type(4)));
typedef unsigned short u16x8 __attribute__((ext_vector_type(8)));
typedef unsigned int   u32x4 __attribute__((ext_vector_type(4)));

__device__ __forceinline__ unsigned short f2bf(float x) {
    unsigned int u = __float_as_uint(x);
    return (unsigned short)((u + 0x7FFFu + ((u >> 16) & 1u)) >> 16);
}
__device__ __forceinline__ float bf2f(unsigned short u) {
    return __uint_as_float((unsigned int)u << 16);
}
__device__ __forceinline__ unsigned int cvtpk(float lo, float hi) {
    unsigned int r;
    asm("v_cvt_pk_bf16_f32 %0, %1, %2" : "=v"(r) : "v"(lo), "v"(hi));
    return r;
}

// ---------------------------------------------------------------------------
// conv: nf -> bf16 (nfb), W_{lin,q,k} -> bf16 transposed (Wt[z][n][k])
// ---------------------------------------------------------------------------
__global__ __launch_bounds__(256) void conv_kernel(
    const float* __restrict__ nf, const float* __restrict__ Wl,
    const float* __restrict__ Wq, const float* __restrict__ Wk,
    unsigned short* __restrict__ nfb, unsigned short* __restrict__ Wt)
{
    const int bid = blockIdx.x, tid = threadIdx.x;
    if (bid < 1024) {
        size_t i = ((size_t)bid * 256 + tid) * 8;
        u16x8 o;
        #pragma unroll
        for (int j = 0; j < 8; j++) o[j] = f2bf(nf[i + j]);
        *(u16x8*)&nfb[i] = o;
    } else {
        int t = (bid - 1024) * 256 + tid;   // 0..196607
        int z = t >> 16;
        int l = t & 65535;
        int k = l & 255, n = l >> 8;
        const float* W = (z == 0) ? Wl : (z == 1 ? Wq : Wk);
        Wt[(size_t)z * 65536 + n * 256 + k] = f2bf(W[k * 256 + n]);
    }
}

// ---------------------------------------------------------------------------
// gemm3: X/q/k = lrelu(nfb @ W + bias), barrier-free fragment GEMM
// ---------------------------------------------------------------------------
__global__ __launch_bounds__(256) void gemm3_kernel(
    const unsigned short* __restrict__ nfb, const unsigned short* __restrict__ Wt3,
    const float* __restrict__ bl,
    unsigned short* __restrict__ qb, unsigned short* __restrict__ kb,
    unsigned short* __restrict__ Xt)
{
    const int z  = blockIdx.z;
    const int m0 = blockIdx.x * 64, n0 = blockIdx.y * 64;
    const int tid = threadIdx.x, wave = tid >> 6, lane = tid & 63;
    const int lq = lane >> 4, lr = lane & 15;
    const unsigned short* Wt = Wt3 + (size_t)z * 65536;

    f32x4 acc[4] = {};
    #pragma unroll 4
    for (int k0 = 0; k0 < IN_; k0 += 32) {
        bf16x8 af = *(const bf16x8*)&nfb[(size_t)(m0 + wave * 16 + lr) * IN_ + k0 + lq * 8];
        #pragma unroll
        for (int f = 0; f < 4; f++) {
            bf16x8 bfr = *(const bf16x8*)&Wt[(size_t)(n0 + f * 16 + lr) * IN_ + k0 + lq * 8];
            acc[f] = __builtin_amdgcn_mfma_f32_16x16x32_bf16(af, bfr, acc[f], 0, 0, 0);
        }
    }

    #pragma unroll
    for (int f = 0; f < 4; f++) {
        int c = n0 + f * 16 + lr;
        float bias = (z == 0) ? bl[c] : 0.0f;
        #pragma unroll
        for (int r = 0; r < 4; r++) {
            int m = m0 + wave * 16 + lq * 4 + r;
            float v = acc[f][r] + bias;
            v = (v >= 0.f) ? v : 0.01f * v;
            unsigned short bv = f2bf(v);
            if (z == 0) {
                int n = m & (N_ - 1);
                int h = c >> 6, d = c & 63;
                Xt[(((size_t)(m >> 11) * H_ + h) * HD_ + d) * N_ + n] = bv;
            } else {
                unsigned short* dst = (z == 1) ? qb : kb;
                dst[(size_t)m * OUT_ + c] = bv;
            }
        }
    }
}

// ---------------------------------------------------------------------------
// att: W[s][x][y] = adj[b][x][y]*sigmoid(q.k/8) (bf16), + row-sum partials
// 128x128 tile per block, 4 waves in 2x2 of 64x64, barrier-free
// ---------------------------------------------------------------------------
__global__ __launch_bounds__(256) void att_kernel(
    const float* __restrict__ adj,
    const unsigned short* __restrict__ qb,
    const unsigned short* __restrict__ kb,
    unsigned short* __restrict__ W,      // chunk: [s_local][N][N]
    float* __restrict__ degp,            // [32][SH][N]
    int b_base, int SH)
{
    const int s  = blockIdx.z;               // local slice
    const int bg = b_base + (s >> 2);
    const int hg = s & 3;
    const int x0 = blockIdx.x * 128, y0 = blockIdx.y * 128;
    const int tid = threadIdx.x, wave = tid >> 6, lane = tid & 63;
    const int lq = lane >> 4, lr = lane & 15;
    const int wq = wave >> 1, wn = wave & 1;
    const int wx0 = x0 + wq * 64, wy0 = y0 + wn * 64;
    const float sc = -0.125f * 1.44269504088896f;

    const unsigned short* qrow = qb + (size_t)(bg * N_ + wx0) * OUT_ + hg * HD_;
    const unsigned short* krow = kb + (size_t)(bg * N_ + wy0) * OUT_ + hg * HD_;

    f32x4 acc[4][4] = {};
    #pragma unroll
    for (int ks = 0; ks < 2; ks++) {
        bf16x8 af[4], bf[4];
        #pragma unroll
        for (int mf = 0; mf < 4; mf++)
            af[mf] = *(const bf16x8*)&qrow[(size_t)(mf * 16 + lr) * OUT_ + ks * 32 + lq * 8];
        #pragma unroll
        for (int nf = 0; nf < 4; nf++)
            bf[nf] = *(const bf16x8*)&krow[(size_t)(nf * 16 + lr) * OUT_ + ks * 32 + lq * 8];
        #pragma unroll
        for (int mf = 0; mf < 4; mf++)
            #pragma unroll
            for (int nf = 0; nf < 4; nf++)
                acc[mf][nf] = __builtin_amdgcn_mfma_f32_16x16x32_bf16(af[mf], bf[nf], acc[mf][nf], 0, 0, 0);
    }

    unsigned short* Wp = W + (size_t)s * N_ * N_;
    #pragma unroll
    for (int mf = 0; mf < 4; mf++) {
        #pragma unroll
        for (int r = 0; r < 4; r++) {
            int x = wx0 + mf * 16 + lq * 4 + r;
            const float* arow = adj + ((size_t)bg * N_ + x) * N_ + wy0;
            unsigned short* wrow = Wp + (size_t)x * N_ + wy0;
            float sum = 0.f;
            #pragma unroll
            for (int nf = 0; nf < 4; nf++) {
                float a = arow[nf * 16 + lr];
                float att = __builtin_amdgcn_rcpf(1.f + exp2f(acc[mf][nf][r] * sc));
                float wv = a * att;
                sum += wv;
                wrow[nf * 16 + lr] = f2bf(wv);
            }
            sum += __shfl_xor(sum, 1); sum += __shfl_xor(sum, 2);
            sum += __shfl_xor(sum, 4); sum += __shfl_xor(sum, 8);
            if (lr == 0)
                degp[((size_t)(blockIdx.y * 2 + wn) * SH + s) * N_ + x] = sum;
        }
    }
}

// ---------------------------------------------------------------------------
// degsum: deg = sum of 32 partials; dis = deg^-1/2
// ---------------------------------------------------------------------------
__global__ __launch_bounds__(256) void degsum_kernel(
    const float* __restrict__ degp, float* __restrict__ dis, int b_base, int SH)
{
    int t = blockIdx.x * 256 + threadIdx.x;    // SH*N threads
    int s = t >> 11, x = t & (N_ - 1);
    float sum = 0.f;
    #pragma unroll
    for (int j = 0; j < 32; j++) sum += degp[((size_t)j * SH + s) * N_ + x];
    dis[((size_t)b_base * H_ + s) * N_ + x] = (sum > 0.f) ? rsqrtf(sum) : 0.f;
}

// ---------------------------------------------------------------------------
// scale: Xs = Xt * dis_y (bf16); pointers pre-offset to chunk
// ---------------------------------------------------------------------------
__global__ __launch_bounds__(256) void scale_kernel(
    const unsigned short* __restrict__ Xt, const float* __restrict__ dis,
    unsigned short* __restrict__ Xs)
{
    int t = blockIdx.x * 256 + threadIdx.x;
    size_t idx = (size_t)t * 8;
    int s = t >> 14;                         // HD*N/8 = 16384
    int y = (int)(idx & (N_ - 1));
    f32x4 d0 = *(const f32x4*)&dis[(size_t)s * N_ + y];
    f32x4 d1 = *(const f32x4*)&dis[(size_t)s * N_ + y + 4];
    u16x8 x = *(const u16x8*)&Xt[idx];
    u32x4 o;
    o[0] = cvtpk(bf2f(x[0]) * d0[0], bf2f(x[1]) * d0[1]);
    o[1] = cvtpk(bf2f(x[2]) * d0[2], bf2f(x[3]) * d0[3]);
    o[2] = cvtpk(bf2f(x[4]) * d1[0], bf2f(x[5]) * d1[1]);
    o[3] = cvtpk(bf2f(x[6]) * d1[2], bf2f(x[7]) * d1[3]);
    *(u32x4*)&Xs[idx] = o;
}

// ---------------------------------------------------------------------------
// yout: Y = W @ Xs (K=2048), * dis_x, fused LayerNorm, write out
// block: 16 rows, 4 waves = 4 heads, barrier-free main loop
// ---------------------------------------------------------------------------
__global__ __launch_bounds__(256) void yout_kernel(
    const unsigned short* __restrict__ W,    // chunk base
    const unsigned short* __restrict__ Xs,   // chunk base
    const float* __restrict__ dis,           // full
    const float* __restrict__ lng, const float* __restrict__ lnb,
    float* __restrict__ out, int b_base)
{
    const int x0 = blockIdx.x * 16;
    const int bl = blockIdx.y;
    const int bg = b_base + bl;
    const int tid = threadIdx.x, h = tid >> 6, lane = tid & 63;
    const int lq = lane >> 4, lr = lane & 15;
    const int s = bl * H_ + h;

    const unsigned short* Wp = W + (size_t)s * N_ * N_ + (size_t)(x0 + lr) * N_;
    const unsigned short* Xp = Xs + ((size_t)s * HD_ + lr) * N_;

    f32x4 Y[4] = {};
    for (int k0 = 0; k0 < N_; k0 += 64) {
        #pragma unroll
        for (int ks = 0; ks < 2; ks++) {
            bf16x8 af = *(const bf16x8*)&Wp[k0 + ks * 32 + lq * 8];
            #pragma unroll
            for (int db = 0; db < 4; db++) {
                bf16x8 xf = *(const bf16x8*)&Xp[(size_t)db * 16 * N_ + k0 + ks * 32 + lq * 8];
                Y[db] = __builtin_amdgcn_mfma_f32_16x16x32_bf16(af, xf, Y[db], 0, 0, 0);
            }
        }
    }

    float dx[4];
    #pragma unroll
    for (int r = 0; r < 4; r++)
        dx[r] = dis[((size_t)bg * H_ + h) * N_ + x0 + lq * 4 + r];

    __shared__ float lnred[2][4][16];
    float s1[4] = {}, s2[4] = {};
    #pragma unroll
    for (int r = 0; r < 4; r++) {
        #pragma unroll
        for (int db = 0; db < 4; db++) {
            float v = Y[db][r] * dx[r];
            s1[r] += v; s2[r] += v * v;
        }
    }
    #pragma unroll
    for (int r = 0; r < 4; r++) {
        float a = s1[r], q2 = s2[r];
        a += __shfl_xor(a, 1); a += __shfl_xor(a, 2); a += __shfl_xor(a, 4); a += __shfl_xor(a, 8);
        q2 += __shfl_xor(q2, 1); q2 += __shfl_xor(q2, 2); q2 += __shfl_xor(q2, 4); q2 += __shfl_xor(q2, 8);
        s1[r] = a; s2[r] = q2;
    }
    if (lr == 0) {
        #pragma unroll
        for (int r = 0; r < 4; r++) {
            lnred[0][h][lq * 4 + r] = s1[r];
            lnred[1][h][lq * 4 + r] = s2[r];
        }
    }
    __syncthreads();

    float gg[4], bb[4];
    #pragma unroll
    for (int db = 0; db < 4; db++) {
        int c = h * HD_ + db * 16 + lr;
        gg[db] = lng[c]; bb[db] = lnb[c];
    }
    #pragma unroll
    for (int r = 0; r < 4; r++) {
        int xr = lq * 4 + r;
        float t1 = lnred[0][0][xr] + lnred[0][1][xr] + lnred[0][2][xr] + lnred[0][3][xr];
        float t2 = lnred[1][0][xr] + lnred[1][1][xr] + lnred[1][2][xr] + lnred[1][3][xr];
        float mu  = t1 * (1.f / 256.f);
        float var = t2 * (1.f / 256.f) - mu * mu;
        float rs  = rsqrtf(var + LN_EPS);
        #pragma unroll
        for (int db = 0; db < 4; db++) {
            int c = h * HD_ + db * 16 + lr;
            float v = (Y[db][r] * dx[r] - mu) * rs * gg[db] + bb[db];
            out[((size_t)(bg * N_ + x0 + xr)) * OUT_ + c] = v;
        }
    }
}

extern "C" void kernel_launch(void* const* d_in, const int* in_sizes, int n_in,
                              void* d_out, int out_size, void* d_ws, size_t ws_size,
                              hipStream_t stream) {
    const float* nf  = (const float*)d_in[0];
    const float* adj = (const float*)d_in[1];
    const float* Wl  = (const float*)d_in[2];
    const float* bl  = (const float*)d_in[3];
    const float* Wq  = (const float*)d_in[4];
    const float* Wk  = (const float*)d_in[5];
    const float* lng = (const float*)d_in[6];
    const float* lnb = (const float*)d_in[7];
    float* out = (float*)d_out;

    // fixed buffers
    char* w = (char*)d_ws;
    unsigned short* nfb = (unsigned short*)w;  w += (size_t)B_ * N_ * IN_ * 2;
    unsigned short* Wt  = (unsigned short*)w;  w += (size_t)3 * IN_ * OUT_ * 2;
    unsigned short* qb  = (unsigned short*)w;  w += (size_t)B_ * N_ * OUT_ * 2;
    unsigned short* kb  = (unsigned short*)w;  w += (size_t)B_ * N_ * OUT_ * 2;
    unsigned short* Xt  = (unsigned short*)w;  w += (size_t)B_ * N_ * OUT_ * 2;
    unsigned short* Xs  = (unsigned short*)w;  w += (size_t)B_ * N_ * OUT_ * 2;
    float* dis = (float*)w;                    w += (size_t)B_ * H_ * N_ * 4;
    size_t fixed = (size_t)(w - (char*)d_ws);

    // nb batches per chunk: 4 if ws fits the full 134MB W buffer, else 1
    size_t need4 = fixed + (size_t)32 * 16 * N_ * 4 + (size_t)16 * N_ * N_ * 2;
    int nb = (ws_size >= need4) ? 4 : 1;
    int SH = nb * H_;
    float* degp = (float*)w;                   w += (size_t)32 * SH * N_ * 4;
    unsigned short* Wbuf = (unsigned short*)w;

    conv_kernel <<<1792, 256, 0, stream>>>(nf, Wl, Wq, Wk, nfb, Wt);
    gemm3_kernel<<<dim3(128, 4, 3), 256, 0, stream>>>(nfb, Wt, bl, qb, kb, Xt);

    for (int b0 = 0; b0 < B_; b0 += nb) {
        size_t xoff = (size_t)b0 * H_ * HD_ * N_;
        att_kernel   <<<dim3(16, 16, SH), 256, 0, stream>>>(adj, qb, kb, Wbuf, degp, b0, SH);
        degsum_kernel<<<SH * N_ / 256, 256, 0, stream>>>(degp, dis, b0, SH);
        scale_kernel <<<SH * HD_ * N_ / 8 / 256, 256, 0, stream>>>(Xt + xoff, dis + (size_t)b0 * H_ * N_, Xs + xoff);
        yout_kernel  <<<dim3(N_ / 16, nb), 256, 0, stream>>>(Wbuf, Xs + xoff, dis, lng, lnb, out, b0);
    }
}